// Round 8
// baseline (115.745 us; speedup 1.0000x reference)
//
#include <hip/hip_runtime.h>

typedef unsigned short u16;
typedef __bf16 bf16x8 __attribute__((ext_vector_type(8)));
typedef float f32x16 __attribute__((ext_vector_type(16)));
typedef unsigned short u16x8 __attribute__((ext_vector_type(8)));

#define DIM 512
#define EPSV 1e-6f
#define MARGIN 0.2f
#define DEPS2 (512.0f * 1e-6f * 1e-6f)
#define BK 32
#define NSLICE (DIM / BK)   // 16
#define RING 3

#define AS1 __attribute__((address_space(1)))
#define AS3 __attribute__((address_space(3)))

__device__ __forceinline__ u16 f2bf(float f) {
    unsigned int u = __float_as_uint(f);
    unsigned int r = (u + 0x7fffu + ((u >> 16) & 1u)) >> 16;
    return (u16)r;
}

// ---------------- Kernel 1: per-row stats + bf16 convert ----------------
__global__ __launch_bounds__(256) void prep_kernel(
        const float* __restrict__ A, const float* __restrict__ P,
        u16* __restrict__ Abf, float* __restrict__ alpha,
        float* __restrict__ beta, float* __restrict__ dap,
        unsigned int* __restrict__ dan2, int N) {
    int row = blockIdx.x * 4 + (threadIdx.x >> 6);
    int lane = threadIdx.x & 63;
    if (row >= N) return;
    const float* a = A + (size_t)row * DIM + lane * 8;
    const float* p = P + (size_t)row * DIM + lane * 8;
    float4 a0 = *(const float4*)(a);
    float4 a1 = *(const float4*)(a + 4);
    float4 p0 = *(const float4*)(p);
    float4 p1 = *(const float4*)(p + 4);
    float av[8] = {a0.x, a0.y, a0.z, a0.w, a1.x, a1.y, a1.z, a1.w};
    float pv[8] = {p0.x, p0.y, p0.z, p0.w, p1.x, p1.y, p1.z, p1.w};
    float sq = 0.f, s = 0.f, dp = 0.f;
    u16x8 ob;
    #pragma unroll
    for (int e = 0; e < 8; ++e) {
        float x = av[e];
        sq = fmaf(x, x, sq);
        s += x;
        float d = x - pv[e] + EPSV;
        dp = fmaf(d, d, dp);
        ob[e] = f2bf(x);
    }
    *reinterpret_cast<u16x8*>(Abf + (size_t)row * DIM + lane * 8) = ob;
    #pragma unroll
    for (int mask = 32; mask; mask >>= 1) {
        sq += __shfl_xor(sq, mask, 64);
        s  += __shfl_xor(s,  mask, 64);
        dp += __shfl_xor(dp, mask, 64);
    }
    if (lane == 0) {
        alpha[row] = fmaf(2.0f * EPSV, s, sq);
        beta[row]  = fmaf(-2.0f * EPSV, s, sq);
        dap[row]   = sqrtf(dp);
        dan2[row]  = 0x7f800000u;   // +inf
    }
}

// ---------------- Kernel 2: 256x128-tile, k16-pipelined Gram + row/col min ----------------
// Tiles (a,b): rows [256a,+256) x cols [128b,+128), kept iff b >= 2a.
// 8 waves (4M x 2N), per-wave 64x64 = acc[2][2] of 32x32x16 frags (64 regs).
// LDS ring-3 x {A[256][32], B[128][32]} u16 row-major with granule rotation
// p = (p_log + (row>>1))&3 (round-7-verified staging/read pair, 0 conflicts).
// k16-granularity software pipeline: double frag sets (+32 VGPR), each 4-MFMA
// cluster executes while the next 4-read burst is in flight; 1 counted-vmcnt
// barrier per slice sits between the two k16 halves.
__global__ __launch_bounds__(512, 4) void gemm_min_kernel(
        const u16* __restrict__ Abf, const float* __restrict__ alpha,
        const float* __restrict__ beta, unsigned int* __restrict__ dan2, int N) {

    __shared__ u16 lds[RING][12288];   // 72 KiB: per slot A=8192 u16, B=4096 u16

    // XCD-chunked bijective swizzle: 1056 = 8 * 132
    int orig = blockIdx.x;
    int v = (orig & 7) * 132 + (orig >> 3);

    // decode v -> (a, btile): offset(a) = a*(65-a), btile = 2a + (v - offset(a))
    int a = (int)((65.0f - sqrtf(4225.0f - 4.0f * (float)v)) * 0.5f);
    while ((a + 1) * (65 - (a + 1)) <= v) ++a;
    while (a * (65 - a) > v) --a;
    int btile = 2 * a + (v - a * (65 - a));
    int ibase = a << 8, jbase = btile << 7;

    int tid = threadIdx.x;
    int wave = tid >> 6, lane = tid & 63;
    int wr = wave >> 1, wc = wave & 1;      // 4 x 2 wave grid, 64x64 per wave
    int h = lane >> 5, c31 = lane & 31;

    // staging (round-7 verified): lane -> (row = base + lane>>2, slot p = lane&3),
    // source granule = inverse rotation
    int srow = lane >> 2;
    int gsrc = ((lane & 3) - ((lane >> 3) & 3)) & 3;
    const u16* pA0 = Abf + (size_t)(ibase + wave * 32 + srow) * DIM + gsrc * 8;
    const u16* pA1 = Abf + (size_t)(ibase + wave * 32 + 16 + srow) * DIM + gsrc * 8;
    const u16* pB  = Abf + (size_t)(jbase + wave * 16 + srow) * DIM + gsrc * 8;

    // ds_read offsets (u16 units) for k16 step s=0; s=1 is ^16 (granule ^2).
    // A row r, k-granule p_log=h: off = r*32 + ((h + (r>>1))&3)*8
    int aOff[2], bOff[2];
    #pragma unroll
    for (int mf = 0; mf < 2; ++mf) {
        int r = wr * 64 + mf * 32 + c31;
        aOff[mf] = r * 32 + ((h + ((r >> 1) & 3)) & 3) * 8;
    }
    #pragma unroll
    for (int nf = 0; nf < 2; ++nf) {
        int c = wc * 64 + nf * 32 + c31;
        bOff[nf] = 8192 + c * 32 + ((h + ((c >> 1) & 3)) & 3) * 8;
    }

    f32x16 acc[2][2];
    #pragma unroll
    for (int mf = 0; mf < 2; ++mf)
        #pragma unroll
        for (int nf = 0; nf < 2; ++nf)
            #pragma unroll
            for (int e = 0; e < 16; ++e) acc[mf][nf][e] = 0.f;

    auto stage = [&](int t, int slot) {
        u16* base = &lds[slot][0];
        __builtin_amdgcn_global_load_lds((const AS1 void*)(pA0 + t * BK),
            (AS3 void*)(base + wave * 1024), 16, 0, 0);
        __builtin_amdgcn_global_load_lds((const AS1 void*)(pA1 + t * BK),
            (AS3 void*)(base + wave * 1024 + 512), 16, 0, 0);
        __builtin_amdgcn_global_load_lds((const AS1 void*)(pB + t * BK),
            (AS3 void*)(base + 8192 + wave * 512), 16, 0, 0);
    };

    bf16x8 afA[2], bfA[2], afB[2], bfB[2];   // even-ks set / odd-ks set

    #define READK(ks, af, bf)                                                   \
        {                                                                       \
            const u16* base_ = &lds[((ks) >> 1) % RING][0];                     \
            const int sx_ = ((ks) & 1) ? 16 : 0;                                \
            af[0] = *reinterpret_cast<const bf16x8*>(base_ + (aOff[0] ^ sx_));  \
            af[1] = *reinterpret_cast<const bf16x8*>(base_ + (aOff[1] ^ sx_));  \
            bf[0] = *reinterpret_cast<const bf16x8*>(base_ + (bOff[0] ^ sx_));  \
            bf[1] = *reinterpret_cast<const bf16x8*>(base_ + (bOff[1] ^ sx_));  \
        }

    #define MM(af, bf)                                                          \
        {                                                                       \
            __builtin_amdgcn_s_setprio(1);                                      \
            acc[0][0] = __builtin_amdgcn_mfma_f32_32x32x16_bf16(af[0], bf[0], acc[0][0], 0, 0, 0); \
            acc[0][1] = __builtin_amdgcn_mfma_f32_32x32x16_bf16(af[0], bf[1], acc[0][1], 0, 0, 0); \
            acc[1][0] = __builtin_amdgcn_mfma_f32_32x32x16_bf16(af[1], bf[0], acc[1][0], 0, 0, 0); \
            acc[1][1] = __builtin_amdgcn_mfma_f32_32x32x16_bf16(af[1], bf[1], acc[1][1], 0, 0, 0); \
            __builtin_amdgcn_s_setprio(0);                                      \
        }

    // prologue
    stage(0, 0);
    stage(1, 1);
    asm volatile("s_waitcnt vmcnt(3)" ::: "memory");
    __builtin_amdgcn_s_barrier();
    __builtin_amdgcn_sched_barrier(0);
    READK(0, afA, bfA);

    #pragma unroll
    for (int t = 0; t < NSLICE; ++t) {
        READK(2 * t + 1, afB, bfB);              // odd k16 of slice t
        if (t + 2 < NSLICE) stage(t + 2, (t + 2) % RING);
        __builtin_amdgcn_sched_barrier(0);
        MM(afA, bfA);                            // ks = 2t (reads above in flight)
        if (t + 1 < NSLICE) {
            if (t + 2 < NSLICE) { asm volatile("s_waitcnt vmcnt(3)" ::: "memory"); }
            else                { asm volatile("s_waitcnt vmcnt(0)" ::: "memory"); }
            __builtin_amdgcn_s_barrier();
            __builtin_amdgcn_sched_barrier(0);
            READK(2 * t + 2, afA, bfA);          // even k16 of slice t+1
            __builtin_amdgcn_sched_barrier(0);
        }
        MM(afB, bfB);                            // ks = 2t+1 (reads above in flight)
    }

    const float INF = __builtin_inff();

    // ---- row-side: rows I, min over this wave's 64 cols (r6-verified layout) ----
    // C/D 32x32: col = lane&31, row = (reg&3) + 8*(reg>>2) + 4*(lane>>5)
    float bb0 = beta[jbase + wc * 64 + c31];
    float bb1 = beta[jbase + wc * 64 + 32 + c31];
    int gcol0 = jbase + wc * 64 + c31;
    int gcol1 = gcol0 + 32;

    #pragma unroll
    for (int mf = 0; mf < 2; ++mf) {
        #pragma unroll
        for (int reg = 0; reg < 16; ++reg) {
            int rl = (reg & 3) + 8 * (reg >> 2);
            int grow = ibase + wr * 64 + mf * 32 + rl + 4 * h;
            float v0 = fmaf(-2.f, acc[mf][0][reg], bb0);
            float v1 = fmaf(-2.f, acc[mf][1][reg], bb1);
            if (grow == gcol0) v0 = INF;
            if (grow == gcol1) v1 = INF;
            float w = fminf(v0, v1);
            w = fminf(w, __shfl_xor(w, 1, 64));
            w = fminf(w, __shfl_xor(w, 2, 64));
            w = fminf(w, __shfl_xor(w, 4, 64));
            w = fminf(w, __shfl_xor(w, 8, 64));
            w = fminf(w, __shfl_xor(w, 16, 64));
            if (c31 == 0) {
                float d2 = fmaxf(alpha[grow] + DEPS2 + w, 0.f);
                atomicMin(dan2 + grow, __float_as_uint(d2));
            }
        }
    }

    // ---- col-side: this wave's 64 cols, min over the wave's 64 rows (diag masked) ----
    {
        float b_w = beta[ibase + wr * 64 + lane];   // this wave's 64 rows
        float cm0 = INF, cm1 = INF;
        #pragma unroll
        for (int mf = 0; mf < 2; ++mf) {
            #pragma unroll
            for (int reg = 0; reg < 16; ++reg) {
                int rl = (reg & 3) + 8 * (reg >> 2);
                int idx = mf * 32 + rl + 4 * h;          // 0..63 within wave's rows
                float bv = __shfl(b_w, idx, 64);
                int rowg = ibase + wr * 64 + idx;
                float c0 = fmaf(-2.f, acc[mf][0][reg], bv);
                float c1 = fmaf(-2.f, acc[mf][1][reg], bv);
                if (rowg == gcol0) c0 = INF;
                if (rowg == gcol1) c1 = INF;
                cm0 = fminf(cm0, c0);
                cm1 = fminf(cm1, c1);
            }
        }
        cm0 = fminf(cm0, __shfl_xor(cm0, 32, 64));
        cm1 = fminf(cm1, __shfl_xor(cm1, 32, 64));
        if (lane < 32) {
            int gc0 = jbase + wc * 64 + lane;
            int gc1 = gc0 + 32;
            float d20 = fmaxf(alpha[gc0] + DEPS2 + cm0, 0.f);
            float d21 = fmaxf(alpha[gc1] + DEPS2 + cm1, 0.f);
            atomicMin(dan2 + gc0, __float_as_uint(d20));
            atomicMin(dan2 + gc1, __float_as_uint(d21));
        }
    }
    #undef READK
    #undef MM
}

// ---------------- Kernel 3: final loss reduction ----------------
__global__ __launch_bounds__(1024) void finalize_kernel(
        const float* __restrict__ dap, const unsigned int* __restrict__ dan2,
        float* __restrict__ out, int N) {
    __shared__ float red[16];
    float sum = 0.f;
    for (int i = threadIdx.x; i < N; i += 1024) {
        float dan = sqrtf(__uint_as_float(dan2[i]));
        float v = dap[i] - dan + MARGIN;
        sum += fmaxf(v, 0.f);
    }
    #pragma unroll
    for (int mask = 32; mask; mask >>= 1) sum += __shfl_xor(sum, mask, 64);
    int lane = threadIdx.x & 63, w = threadIdx.x >> 6;
    if (lane == 0) red[w] = sum;
    __syncthreads();
    if (threadIdx.x == 0) {
        float tot = 0.f;
        #pragma unroll
        for (int k = 0; k < 16; ++k) tot += red[k];
        out[0] = tot / (float)N;
    }
}

extern "C" void kernel_launch(void* const* d_in, const int* in_sizes, int n_in,
                              void* d_out, int out_size, void* d_ws, size_t ws_size,
                              hipStream_t stream) {
    const float* anchor   = (const float*)d_in[0];
    const float* positive = (const float*)d_in[1];
    int N = in_sizes[0] / DIM;   // 8192
    float* out = (float*)d_out;

    char* ws = (char*)d_ws;
    float* alpha = (float*)ws;
    float* beta  = alpha + N;
    float* dap   = beta + N;
    unsigned int* dan2 = (unsigned int*)(dap + N);
    u16* Abf = (u16*)(dan2 + N);   // N*DIM bf16 = 8.4 MB

    prep_kernel<<<N / 4, 256, 0, stream>>>(anchor, positive, Abf, alpha, beta, dap, dan2, N);
    // kept tiles: (a, b) with b >= 2a; count = sum_a (64-2a) = 1056 = 8*132
    gemm_min_kernel<<<1056, 512, 0, stream>>>(Abf, alpha, beta, dan2, N);
    finalize_kernel<<<1, 1024, 0, stream>>>(dap, dan2, out, N);
}

// Round 9
// 69.830 us; speedup vs baseline: 1.6575x; 1.6575x over previous
//
#include <hip/hip_runtime.h>

typedef unsigned short u16;
typedef __bf16 bf16x8 __attribute__((ext_vector_type(8)));
typedef float f32x4 __attribute__((ext_vector_type(4)));
typedef unsigned short u16x8 __attribute__((ext_vector_type(8)));

#define DIM 512
#define EPSV 1e-6f
#define MARGIN 0.2f
#define DEPS2 (512.0f * 1e-6f * 1e-6f)
#define BK 32
#define NSLICE (DIM / BK)   // 16
#define RING 3

#define AS1 __attribute__((address_space(1)))
#define AS3 __attribute__((address_space(3)))

__device__ __forceinline__ u16 f2bf(float f) {
    unsigned int u = __float_as_uint(f);
    unsigned int r = (u + 0x7fffu + ((u >> 16) & 1u)) >> 16;
    return (u16)r;
}

// ---------------- Kernel 1: per-row stats + bf16 convert ----------------
__global__ __launch_bounds__(256) void prep_kernel(
        const float* __restrict__ A, const float* __restrict__ P,
        u16* __restrict__ Abf, float* __restrict__ alpha,
        float* __restrict__ beta, float* __restrict__ dap,
        unsigned int* __restrict__ dan2, int N) {
    int row = blockIdx.x * 4 + (threadIdx.x >> 6);
    int lane = threadIdx.x & 63;
    if (row >= N) return;
    const float* a = A + (size_t)row * DIM + lane * 8;
    const float* p = P + (size_t)row * DIM + lane * 8;
    float4 a0 = *(const float4*)(a);
    float4 a1 = *(const float4*)(a + 4);
    float4 p0 = *(const float4*)(p);
    float4 p1 = *(const float4*)(p + 4);
    float av[8] = {a0.x, a0.y, a0.z, a0.w, a1.x, a1.y, a1.z, a1.w};
    float pv[8] = {p0.x, p0.y, p0.z, p0.w, p1.x, p1.y, p1.z, p1.w};
    float sq = 0.f, s = 0.f, dp = 0.f;
    u16x8 ob;
    #pragma unroll
    for (int e = 0; e < 8; ++e) {
        float x = av[e];
        sq = fmaf(x, x, sq);
        s += x;
        float d = x - pv[e] + EPSV;
        dp = fmaf(d, d, dp);
        ob[e] = f2bf(x);
    }
    *reinterpret_cast<u16x8*>(Abf + (size_t)row * DIM + lane * 8) = ob;
    #pragma unroll
    for (int mask = 32; mask; mask >>= 1) {
        sq += __shfl_xor(sq, mask, 64);
        s  += __shfl_xor(s,  mask, 64);
        dp += __shfl_xor(dp, mask, 64);
    }
    if (lane == 0) {
        alpha[row] = fmaf(2.0f * EPSV, s, sq);
        beta[row]  = fmaf(-2.0f * EPSV, s, sq);
        dap[row]   = sqrtf(dp);
        dan2[row]  = 0x7f800000u;   // +inf
    }
}

// ---------------- Kernel 2: 256x128-tile ring-3 Gram + row/col min ----------------
// Round-7 verified structure (54 us, absmax 0.0) + ONE change: T5 setprio
// around the MFMA cluster (breaks read/MFMA lockstep between the 2 co-resident
// blocks; m218b/m224 mechanism).
__global__ __launch_bounds__(512, 4) void gemm_min_kernel(
        const u16* __restrict__ Abf, const float* __restrict__ alpha,
        const float* __restrict__ beta, unsigned int* __restrict__ dan2, int N) {

    __shared__ u16 lds[RING][12288];   // 72 KiB: per slot A=8192 u16, B=4096 u16

    // XCD-chunked bijective swizzle: 1056 = 8 * 132
    int orig = blockIdx.x;
    int v = (orig & 7) * 132 + (orig >> 3);

    // decode v -> (a, btile): offset(a) = a*(65-a), btile = 2a + (v - offset(a))
    int a = (int)((65.0f - sqrtf(4225.0f - 4.0f * (float)v)) * 0.5f);
    while ((a + 1) * (65 - (a + 1)) <= v) ++a;
    while (a * (65 - a) > v) --a;
    int btile = 2 * a + (v - a * (65 - a));
    int ibase = a << 8, jbase = btile << 7;

    int tid = threadIdx.x;
    int wave = tid >> 6, lane = tid & 63;
    int wr = wave >> 1, wc = wave & 1;      // 4 x 2 wave grid
    int g = lane >> 4, tl = lane & 15;

    // staging: lane covers (row = base + lane>>2, granule-slot p = lane&3);
    // source granule = inverse rotation (round-3/7 verified pair)
    int srow = lane >> 2;
    int gsrc = ((lane & 3) - ((lane >> 3) & 3)) & 3;
    const u16* pA0 = Abf + (size_t)(ibase + wave * 32 + srow) * DIM + gsrc * 8;
    const u16* pA1 = Abf + (size_t)(ibase + wave * 32 + 16 + srow) * DIM + gsrc * 8;
    const u16* pB  = Abf + (size_t)(jbase + wave * 16 + srow) * DIM + gsrc * 8;

    // ds_read offsets (u16): row r granule-slot p at r*32 + p*8, p=(g+(tl>>1)&3)&3
    int swz = (g + ((tl >> 1) & 3)) & 3;
    int aOff[4], bOff[4];
    #pragma unroll
    for (int mf = 0; mf < 4; ++mf)
        aOff[mf] = (wr * 64 + mf * 16 + tl) * 32 + swz * 8;
    #pragma unroll
    for (int nf = 0; nf < 4; ++nf)
        bOff[nf] = 8192 + (wc * 64 + nf * 16 + tl) * 32 + swz * 8;

    f32x4 acc[4][4];
    f32x4 zero = {0.f, 0.f, 0.f, 0.f};
    #pragma unroll
    for (int mf = 0; mf < 4; ++mf)
        #pragma unroll
        for (int nf = 0; nf < 4; ++nf) acc[mf][nf] = zero;

    auto stage = [&](int t, int slot) {
        u16* base = &lds[slot][0];
        __builtin_amdgcn_global_load_lds((const AS1 void*)(pA0 + t * BK),
            (AS3 void*)(base + wave * 1024), 16, 0, 0);
        __builtin_amdgcn_global_load_lds((const AS1 void*)(pA1 + t * BK),
            (AS3 void*)(base + wave * 1024 + 512), 16, 0, 0);
        __builtin_amdgcn_global_load_lds((const AS1 void*)(pB + t * BK),
            (AS3 void*)(base + 8192 + wave * 512), 16, 0, 0);
    };

    // prologue: stage slices 0,1; certify slice 0 (slice 1's 3 loads in flight)
    stage(0, 0);
    stage(1, 1);
    asm volatile("s_waitcnt vmcnt(3)" ::: "memory");
    __builtin_amdgcn_s_barrier();
    __builtin_amdgcn_sched_barrier(0);

    #pragma unroll
    for (int t = 0; t < NSLICE; ++t) {
        const int slot = t % RING;
        if (t + 2 < NSLICE) stage(t + 2, (t + 2) % RING);

        bf16x8 af[4], bf4[4];
        #pragma unroll
        for (int mf = 0; mf < 4; ++mf)
            af[mf] = *reinterpret_cast<const bf16x8*>(&lds[slot][aOff[mf]]);
        #pragma unroll
        for (int nf = 0; nf < 4; ++nf)
            bf4[nf] = *reinterpret_cast<const bf16x8*>(&lds[slot][bOff[nf]]);

        __builtin_amdgcn_s_setprio(1);
        #pragma unroll
        for (int mf = 0; mf < 4; ++mf)
            #pragma unroll
            for (int nf = 0; nf < 4; ++nf)
                acc[mf][nf] = __builtin_amdgcn_mfma_f32_16x16x32_bf16(
                    af[mf], bf4[nf], acc[mf][nf], 0, 0, 0);
        __builtin_amdgcn_s_setprio(0);

        if (t + 1 < NSLICE) {
            if (t + 2 < NSLICE) { asm volatile("s_waitcnt vmcnt(3)" ::: "memory"); }
            else                { asm volatile("s_waitcnt vmcnt(0)" ::: "memory"); }
            __builtin_amdgcn_s_barrier();
            __builtin_amdgcn_sched_barrier(0);
        }
    }

    const float INF = __builtin_inff();

    // ---- row-side: rows I, min over this wave's 64 cols ----
    // C/D 16x16x32 layout: col = lane&15, row = (lane>>4)*4 + reg  (verified r1-3)
    float bb[4];
    #pragma unroll
    for (int nf = 0; nf < 4; ++nf) bb[nf] = beta[jbase + wc * 64 + nf * 16 + tl];

    #pragma unroll
    for (int mf = 0; mf < 4; ++mf) {
        int grow0 = ibase + wr * 64 + mf * 16 + g * 4;
        float mn0 = INF, mn1 = INF, mn2 = INF, mn3 = INF;
        #pragma unroll
        for (int nf = 0; nf < 4; ++nf) {
            int gcol = jbase + wc * 64 + nf * 16 + tl;
            float c0 = fmaf(-2.f, acc[mf][nf][0], bb[nf]);
            float c1 = fmaf(-2.f, acc[mf][nf][1], bb[nf]);
            float c2 = fmaf(-2.f, acc[mf][nf][2], bb[nf]);
            float c3 = fmaf(-2.f, acc[mf][nf][3], bb[nf]);
            if (grow0 + 0 == gcol) c0 = INF;
            if (grow0 + 1 == gcol) c1 = INF;
            if (grow0 + 2 == gcol) c2 = INF;
            if (grow0 + 3 == gcol) c3 = INF;
            mn0 = fminf(mn0, c0);
            mn1 = fminf(mn1, c1);
            mn2 = fminf(mn2, c2);
            mn3 = fminf(mn3, c3);
        }
        #pragma unroll
        for (int mask = 1; mask < 16; mask <<= 1) {
            mn0 = fminf(mn0, __shfl_xor(mn0, mask, 64));
            mn1 = fminf(mn1, __shfl_xor(mn1, mask, 64));
            mn2 = fminf(mn2, __shfl_xor(mn2, mask, 64));
            mn3 = fminf(mn3, __shfl_xor(mn3, mask, 64));
        }
        if (tl == 0) {
            float d20 = fmaxf(alpha[grow0 + 0] + DEPS2 + mn0, 0.f);
            float d21 = fmaxf(alpha[grow0 + 1] + DEPS2 + mn1, 0.f);
            float d22 = fmaxf(alpha[grow0 + 2] + DEPS2 + mn2, 0.f);
            float d23 = fmaxf(alpha[grow0 + 3] + DEPS2 + mn3, 0.f);
            atomicMin(dan2 + grow0 + 0, __float_as_uint(d20));
            atomicMin(dan2 + grow0 + 1, __float_as_uint(d21));
            atomicMin(dan2 + grow0 + 2, __float_as_uint(d22));
            atomicMin(dan2 + grow0 + 3, __float_as_uint(d23));
        }
    }

    // ---- col-side: this wave's 64 cols, min over the wave's 64 rows (diag masked) ----
    #pragma unroll
    for (int nf = 0; nf < 4; ++nf) {
        int gcol = jbase + wc * 64 + nf * 16 + tl;
        float cm = INF;
        #pragma unroll
        for (int mf = 0; mf < 4; ++mf) {
            int grow0 = ibase + wr * 64 + mf * 16 + g * 4;
            #pragma unroll
            for (int e = 0; e < 4; ++e) {
                int rowg = grow0 + e;
                float c = fmaf(-2.f, acc[mf][nf][e], beta[rowg]);
                if (rowg == gcol) c = INF;
                cm = fminf(cm, c);
            }
        }
        cm = fminf(cm, __shfl_xor(cm, 16, 64));
        cm = fminf(cm, __shfl_xor(cm, 32, 64));
        if (g == 0) {
            float d2 = fmaxf(alpha[gcol] + DEPS2 + cm, 0.f);
            atomicMin(dan2 + gcol, __float_as_uint(d2));
        }
    }
}

// ---------------- Kernel 3: final loss reduction ----------------
__global__ __launch_bounds__(1024) void finalize_kernel(
        const float* __restrict__ dap, const unsigned int* __restrict__ dan2,
        float* __restrict__ out, int N) {
    __shared__ float red[16];
    float sum = 0.f;
    for (int i = threadIdx.x; i < N; i += 1024) {
        float dan = sqrtf(__uint_as_float(dan2[i]));
        float v = dap[i] - dan + MARGIN;
        sum += fmaxf(v, 0.f);
    }
    #pragma unroll
    for (int mask = 32; mask; mask >>= 1) sum += __shfl_xor(sum, mask, 64);
    int lane = threadIdx.x & 63, w = threadIdx.x >> 6;
    if (lane == 0) red[w] = sum;
    __syncthreads();
    if (threadIdx.x == 0) {
        float tot = 0.f;
        #pragma unroll
        for (int k = 0; k < 16; ++k) tot += red[k];
        out[0] = tot / (float)N;
    }
}

extern "C" void kernel_launch(void* const* d_in, const int* in_sizes, int n_in,
                              void* d_out, int out_size, void* d_ws, size_t ws_size,
                              hipStream_t stream) {
    const float* anchor   = (const float*)d_in[0];
    const float* positive = (const float*)d_in[1];
    int N = in_sizes[0] / DIM;   // 8192
    float* out = (float*)d_out;

    char* ws = (char*)d_ws;
    float* alpha = (float*)ws;
    float* beta  = alpha + N;
    float* dap   = beta + N;
    unsigned int* dan2 = (unsigned int*)(dap + N);
    u16* Abf = (u16*)(dan2 + N);   // N*DIM bf16 = 8.4 MB

    prep_kernel<<<N / 4, 256, 0, stream>>>(anchor, positive, Abf, alpha, beta, dap, dan2, N);
    // kept tiles: (a, b) with b >= 2a; count = sum_a (64-2a) = 1056 = 8*132
    gemm_min_kernel<<<1056, 512, 0, stream>>>(Abf, alpha, beta, dan2, N);
    finalize_kernel<<<1, 1024, 0, stream>>>(dap, dan2, out, N);
}